// Round 16
// baseline (49.751 us; speedup 1.0000x reference)
//
#include <hip/hip_runtime.h>
#include <math.h>

// Problem constants (fixed shapes from reference)
#define BATCH   8
#define HGRID   64
#define WGRID   64
#define DDIM    256
#define NPTS    1024
#define ROWS    65          // HGRID + 1 (NaN pad row 0)
#define COLS    65
#define KWIN    15          // (2*R_WIN+1)*(2*C_WIN+1) = 3*5
#define BN      (BATCH*NPTS)

#define PIDS_PER_BLK 16
#define THREADS      512    // 8 waves; Phase B: 2 pids per wave
#define NREG         9      // staged q rows in registers
#define NLDS         6      // staged q rows in LDS (per wave slab)
#define CT_BLOCKS    (BN * DDIM / 1024)   // 2048

typedef __attribute__((ext_vector_type(8))) short bf16x8;
typedef __attribute__((ext_vector_type(4))) float f32x4;

// Direct-to-LDS 16B/lane: dest = wave-uniform base + lane*16.
__device__ __forceinline__ void gload_lds16(const float* src, float* dst) {
    __builtin_amdgcn_global_load_lds(
        (const __attribute__((address_space(1))) unsigned int*)src,
        (__attribute__((address_space(3))) unsigned int*)dst, 16, 0, 0);
}

// ---------------------------------------------------------------------------
// Kernel 1 (prep, R9-proven): c_t -> CH/CL (bf16 hi + residual);
// W_a -> WHT/WLT[d][c] transposed splits.
// ---------------------------------------------------------------------------
__global__ __launch_bounds__(256) void prep(const float* __restrict__ ct,
                                            const float* __restrict__ W,
                                            ushort* __restrict__ CH,
                                            ushort* __restrict__ CL,
                                            ushort* __restrict__ WHT,
                                            ushort* __restrict__ WLT) {
    const int bid = blockIdx.x;
    if (bid < CT_BLOCKS) {
        const int i = (bid * 256 + threadIdx.x) * 4;
        const float4 v = *reinterpret_cast<const float4*>(&ct[i]);
        const float f[4] = {v.x, v.y, v.z, v.w};
        ushort h[4], l[4];
        #pragma unroll
        for (int e = 0; e < 4; ++e) {
            const unsigned u = __float_as_uint(f[e]);
            h[e] = (ushort)(u >> 16);
            const float res = f[e] - __uint_as_float(u & 0xFFFF0000u);
            l[e] = (ushort)(__float_as_uint(res) >> 16);
        }
        *reinterpret_cast<ushort4*>(&CH[i]) = make_ushort4(h[0], h[1], h[2], h[3]);
        *reinterpret_cast<ushort4*>(&CL[i]) = make_ushort4(l[0], l[1], l[2], l[3]);
    } else {
        const int d = bid - CT_BLOCKS;
        const int c = threadIdx.x;
        const float f = W[c * DDIM + d];
        const unsigned u = __float_as_uint(f);
        const float res = f - __uint_as_float(u & 0xFFFF0000u);
        WHT[d * DDIM + c] = (ushort)(u >> 16);
        WLT[d * DDIM + c] = (ushort)(__float_as_uint(res) >> 16);
    }
}

// ---------------------------------------------------------------------------
// Kernel 2 (fused v11) = v10 (33.7us best: hybrid gather + XCD swizzle)
// with Phase A consuming PRE-CONVERTED operands: per kt = 6 uint4 loads +
// 6 MFMA, zero conversion VALU (was ~140 VALU + 18 loads).
// ---------------------------------------------------------------------------
__global__ __launch_bounds__(THREADS, 4) void fused_local_attn(
        const float* __restrict__ q,
        const float* __restrict__ p_t,
        const ushort* __restrict__ CH,
        const ushort* __restrict__ CL,
        const ushort* __restrict__ WHT,
        const ushort* __restrict__ WLT,
        float* __restrict__ out) {

    __shared__ __align__(16) float smem[NLDS * DDIM * 8];   // 48 KB
    float (*Pr)[DDIM] = reinterpret_cast<float (*)[DDIM]>(smem);  // 16KB alias

    const int t    = threadIdx.x;
    const int w    = t >> 6;          // wave 0..7
    const int lane = t & 63;
    const int l15  = lane & 15;
    const int g    = lane >> 4;       // k-group 0..3
    const int bid  = blockIdx.x;
    const int wk   = (bid & 7) * 64 + (bid >> 3);   // XCD-aligned work index
    const int pid0 = wk * PIDS_PER_BLK;
    const int dq   = w * 32;          // this wave's 32-col d-slice
    float* qsw = smem + w * (NLDS * DDIM);   // this wave's staging slab

    // ---------------- Phase A: slim MFMA proj into LDS --------------------
    f32x4 acc0 = (f32x4)0.f;
    f32x4 acc1 = (f32x4)0.f;

    const ushort* chp = &CH[(size_t)(pid0 + l15) * DDIM + g * 8];
    const ushort* clp = &CL[(size_t)(pid0 + l15) * DDIM + g * 8];
    const ushort* wh0 = &WHT[(size_t)(dq + l15) * DDIM + g * 8];
    const ushort* wl0 = &WLT[(size_t)(dq + l15) * DDIM + g * 8];
    const ushort* wh1 = wh0 + (size_t)16 * DDIM;
    const ushort* wl1 = wl0 + (size_t)16 * DDIM;

    #pragma unroll 2
    for (int kt = 0; kt < 8; ++kt) {
        union { uint4 u; bf16x8 v; } AH, AL, BH0, BL0, BH1, BL1;
        AH.u  = *reinterpret_cast<const uint4*>(chp + kt * 32);
        AL.u  = *reinterpret_cast<const uint4*>(clp + kt * 32);
        BH0.u = *reinterpret_cast<const uint4*>(wh0 + kt * 32);
        BL0.u = *reinterpret_cast<const uint4*>(wl0 + kt * 32);
        BH1.u = *reinterpret_cast<const uint4*>(wh1 + kt * 32);
        BL1.u = *reinterpret_cast<const uint4*>(wl1 + kt * 32);
        acc0 = __builtin_amdgcn_mfma_f32_16x16x32_bf16(AH.v, BH0.v, acc0, 0, 0, 0);
        acc0 = __builtin_amdgcn_mfma_f32_16x16x32_bf16(AH.v, BL0.v, acc0, 0, 0, 0);
        acc0 = __builtin_amdgcn_mfma_f32_16x16x32_bf16(AL.v, BH0.v, acc0, 0, 0, 0);
        acc1 = __builtin_amdgcn_mfma_f32_16x16x32_bf16(AH.v, BH1.v, acc1, 0, 0, 0);
        acc1 = __builtin_amdgcn_mfma_f32_16x16x32_bf16(AH.v, BL1.v, acc1, 0, 0, 0);
        acc1 = __builtin_amdgcn_mfma_f32_16x16x32_bf16(AL.v, BH1.v, acc1, 0, 0, 0);
    }

    // C/D layout: col = lane&15, row = (lane>>4)*4 + reg  [m89-verified]
    #pragma unroll
    for (int r = 0; r < 4; ++r) {
        Pr[g * 4 + r][dq +  0 + l15] = acc0[r];
        Pr[g * 4 + r][dq + 16 + l15] = acc1[r];
    }
    __syncthreads();

    // Snapshot both pr rows, then Pr's LDS is recycled as staging space.
    const float4 prA = *reinterpret_cast<const float4*>(&Pr[w * 2 + 0][lane * 4]);
    const float4 prB = *reinterpret_cast<const float4*>(&Pr[w * 2 + 1][lane * 4]);
    __syncthreads();

    // ---------------- Phase B: attention, 2 pids per wave (v10 verbatim) --
    #pragma unroll 1
    for (int pp = 0; pp < 2; ++pp) {
        const int pl  = w * 2 + pp;            // pid-local 0..15
        const int pid = pid0 + pl;
        const int b   = pid >> 10;             // / NPTS
        const float4 pr = pp ? prB : prA;
        const float2 ppos = *reinterpret_cast<const float2*>(&p_t[pid * 2]);
        const float p0f = ppos.x;
        const float p1f = ppos.y;
        const int p0 = (int)p0f;
        const int p1 = (int)p1f;

        float re[3], ce[5];
        int rowidx[3], colidx[5];
        #pragma unroll
        for (int i = 0; i < 3; ++i) {
            int rr = p0 + i;
            rr = rr > ROWS ? ROWS : rr;
            rr = (rr == ROWS) ? 0 : rr;        // % ROWS
            rowidx[i] = rr;
            const float rf = (float)(rr - 1 > 0 ? rr - 1 : 0);
            const float dr = rf - p0f;         // / R_WIN (=1)
            re[i] = __expf(-2.0f * dr * dr);
        }
        #pragma unroll
        for (int j = 0; j < 5; ++j) {
            int cc = p1 + j - 1;
            cc = cc < 0 ? 0 : (cc > COLS ? COLS : cc);
            cc = (cc == COLS) ? 0 : cc;        // % COLS
            colidx[j] = cc;
            const float cf = (float)(cc - 1 > 0 ? cc - 1 : 0);
            const float dc = (cf - p1f) * 0.5f; // / C_WIN (=2)
            ce[j] = __expf(-2.0f * dc * dc);
        }

        // Fence: previous round's LDS reads must retire before async writes
        // to the same slab can be issued (vmcnt and lgkmcnt are separate).
        asm volatile("s_waitcnt lgkmcnt(0)" ::: "memory");
        __builtin_amdgcn_sched_barrier(0);

        // ---- Issue ALL 15 gathers: rows 0..NREG-1 -> regs, rest -> LDS ----
        float4 qg[NREG];
        unsigned vmask = 0;
        #pragma unroll
        for (int k = 0; k < KWIN; ++k) {
            const int i = k / 5, j = k % 5;
            const int rr = rowidx[i];
            const int cc = colidx[j];
            const bool valid = (rr != 0) && (cc != 0);   // wave-uniform
            const float* src =
                &q[((size_t)((b * HGRID + rr - 1) * WGRID + cc - 1)) * DDIM + lane * 4];
            if (k < NREG) {
                float4 v = make_float4(0.f, 0.f, 0.f, 0.f);
                if (valid) v = *reinterpret_cast<const float4*>(src);
                qg[k] = v;
            } else {
                if (valid) gload_lds16(src, &qsw[(k - NREG) * DDIM]);
            }
            if (valid) vmask |= (1u << k);
        }
        asm volatile("s_waitcnt vmcnt(0)" ::: "memory");   // ONE wait for all 15
        // Pin register rows once (post-drain: no serialization, no remat).
        #pragma unroll
        for (int k = 0; k < NREG; ++k)
            asm volatile("" : "+v"(qg[k].x), "+v"(qg[k].y), "+v"(qg[k].z), "+v"(qg[k].w));

        // ---- Scores ----
        float score[KWIN];
        #pragma unroll
        for (int k = 0; k < NREG; ++k) {
            const float4 v = qg[k];
            score[k] = fmaf(v.x, pr.x, fmaf(v.y, pr.y, fmaf(v.z, pr.z, v.w * pr.w)));
        }
        #pragma unroll
        for (int k = NREG; k < KWIN; ++k) {
            const float4 v =
                *reinterpret_cast<const float4*>(&qsw[(k - NREG) * DDIM + lane * 4]);
            score[k] = fmaf(v.x, pr.x, fmaf(v.y, pr.y, fmaf(v.z, pr.z, v.w * pr.w)));
        }

        // ---- 15 independent butterfly reductions ----
        #pragma unroll
        for (int k = 0; k < KWIN; ++k) {
            float s = score[k];
            #pragma unroll
            for (int off = 32; off; off >>= 1) s += __shfl_xor(s, off, 64);
            score[k] = ((vmask >> k) & 1u) ? s : -INFINITY;
        }

        // ---- Softmax over K=15 (replicated across lanes) ----
        float mx = score[0];
        #pragma unroll
        for (int k = 1; k < KWIN; ++k) mx = fmaxf(mx, score[k]);
        float sum = 0.f;
        #pragma unroll
        for (int k = 0; k < KWIN; ++k) {
            const float e = __expf(score[k] - mx);
            score[k] = e;
            sum += e;
        }
        const float inv = 1.0f / sum;

        // ---- Weighted sum: reg rows + LDS rows ----
        float ox = 0.f, oy = 0.f, oz = 0.f, ow = 0.f;
        #pragma unroll
        for (int k = 0; k < KWIN; ++k) {
            const int i = k / 5, j = k % 5;
            const float wk2 = score[k] * inv * re[i] * ce[j];
            if (k < NREG) {
                ox = fmaf(wk2, qg[k].x, ox);
                oy = fmaf(wk2, qg[k].y, oy);
                oz = fmaf(wk2, qg[k].z, oz);
                ow = fmaf(wk2, qg[k].w, ow);
            } else if ((vmask >> k) & 1u) {   // guard: stale LDS may be NaN
                const float4 v =
                    *reinterpret_cast<const float4*>(&qsw[(k - NREG) * DDIM + lane * 4]);
                ox = fmaf(wk2, v.x, ox);
                oy = fmaf(wk2, v.y, oy);
                oz = fmaf(wk2, v.z, oz);
                ow = fmaf(wk2, v.w, ow);
            }
        }
        *reinterpret_cast<float4*>(&out[(size_t)pid * DDIM + lane * 4]) =
            make_float4(ox, oy, oz, ow);
    }
}

// ---------------------------------------------------------------------------
extern "C" void kernel_launch(void* const* d_in, const int* in_sizes, int n_in,
                              void* d_out, int out_size, void* d_ws, size_t ws_size,
                              hipStream_t stream) {
    const float* q   = (const float*)d_in[0];
    const float* c_t = (const float*)d_in[1];
    const float* p_t = (const float*)d_in[2];
    const float* W_a = (const float*)d_in[3];
    float* out = (float*)d_out;

    char* ws = (char*)d_ws;
    ushort* CH  = (ushort*)ws;                              // 4 MB
    ushort* CL  = (ushort*)(ws + (4 << 20));                // 4 MB
    ushort* WHT = (ushort*)(ws + (8 << 20));                // 128 KB
    ushort* WLT = (ushort*)(ws + (8 << 20) + DDIM * DDIM * 2);

    prep<<<CT_BLOCKS + DDIM, 256, 0, stream>>>(c_t, W_a, CH, CL, WHT, WLT);

    fused_local_attn<<<BN / PIDS_PER_BLK, THREADS, 0, stream>>>(
        q, p_t, CH, CL, WHT, WLT, out);
}

// Round 17
// 35.549 us; speedup vs baseline: 1.3995x; 1.3995x over previous
//
#include <hip/hip_runtime.h>
#include <math.h>

// Problem constants (fixed shapes from reference)
#define BATCH   8
#define HGRID   64
#define WGRID   64
#define DDIM    256
#define NPTS    1024
#define ROWS    65          // HGRID + 1 (NaN pad row 0)
#define COLS    65
#define KWIN    15          // (2*R_WIN+1)*(2*C_WIN+1) = 3*5
#define BN      (BATCH*NPTS)

#define PIDS_PER_BLK 16
#define THREADS      512    // 8 waves; Phase B: 2 pids per wave (pipelined)
#define NREG         9      // staged q rows in registers
#define NLDS         6      // staged q rows in LDS (per wave slab)

typedef __attribute__((ext_vector_type(8))) short bf16x8;
typedef __attribute__((ext_vector_type(4))) float f32x4;

// Direct-to-LDS 16B/lane: dest = wave-uniform base + lane*16.
__device__ __forceinline__ void gload_lds16(const float* src, float* dst) {
    __builtin_amdgcn_global_load_lds(
        (const __attribute__((address_space(1))) unsigned int*)src,
        (__attribute__((address_space(3))) unsigned int*)dst, 16, 0, 0);
}

// ---------------------------------------------------------------------------
// Fused v12 = v10 (33.7us best) with software-pipelined Phase B:
//   issue pid0's 15 gathers, then pid1's 9 REG gathers (order pinned by
//   sched_barrier), wait vmcnt(9) == pid0 complete, compute pid0 while
//   pid1's reg loads fly; then fence slab, issue pid1's 6 LDS gathers,
//   overlap re/ce VALU, vmcnt(0), compute pid1.
// Phase A, XCD swizzle, hybrid engine: v10 verbatim.
// ---------------------------------------------------------------------------
__global__ __launch_bounds__(THREADS, 4) void fused_local_attn(
        const float* __restrict__ q,
        const float* __restrict__ c_t,
        const float* __restrict__ p_t,
        const float* __restrict__ W,
        float* __restrict__ out) {

    __shared__ __align__(16) float smem[NLDS * DDIM * 8];   // 48 KB
    float (*Pr)[DDIM] = reinterpret_cast<float (*)[DDIM]>(smem);  // 16KB alias

    const int t    = threadIdx.x;
    const int w    = t >> 6;          // wave 0..7
    const int lane = t & 63;
    const int l15  = lane & 15;
    const int g    = lane >> 4;       // k-group 0..3
    const int bid  = blockIdx.x;
    const int wk   = (bid & 7) * 64 + (bid >> 3);   // XCD-aligned work index
    const int pid0 = wk * PIDS_PER_BLK;
    const int dq   = w * 32;          // this wave's 32-col d-slice
    float* qsw = smem + w * (NLDS * DDIM);   // this wave's staging slab

    // ---------------- Phase A: proj into LDS (v10 verbatim) ---------------
    f32x4 acc0 = (f32x4)0.f;
    f32x4 acc1 = (f32x4)0.f;

    const float* ap  = &c_t[(size_t)(pid0 + l15) * DDIM + g * 8];
    const float* wp0 = &W[(size_t)(g * 8) * DDIM + dq + l15];        // df=0
    const float* wp1 = wp0 + 16;                                      // df=1

    #pragma unroll 2
    for (int kt = 0; kt < 8; ++kt) {
        const float4 a01 = *reinterpret_cast<const float4*>(ap + kt * 32);
        const float4 a23 = *reinterpret_cast<const float4*>(ap + kt * 32 + 4);
        const float af[8] = {a01.x, a01.y, a01.z, a01.w, a23.x, a23.y, a23.z, a23.w};
        union { bf16x8 v; unsigned u[4]; } AH, AL;
        #pragma unroll
        for (int i = 0; i < 4; ++i) {
            const unsigned u0 = __float_as_uint(af[2 * i]);
            const unsigned u1 = __float_as_uint(af[2 * i + 1]);
            AH.u[i] = __builtin_amdgcn_perm(u1, u0, 0x07060302u);
            const float l0 = af[2 * i]     - __uint_as_float(u0 & 0xFFFF0000u);
            const float l1 = af[2 * i + 1] - __uint_as_float(u1 & 0xFFFF0000u);
            AL.u[i] = __builtin_amdgcn_perm(__float_as_uint(l1), __float_as_uint(l0),
                                            0x07060302u);
        }

        #pragma unroll
        for (int df = 0; df < 2; ++df) {
            const float* wp = (df == 0) ? wp0 : wp1;
            float bf[8];
            #pragma unroll
            for (int i = 0; i < 8; ++i)
                bf[i] = wp[(size_t)(kt * 32 + i) * DDIM];
            union { bf16x8 v; unsigned u[4]; } BH, BL;
            #pragma unroll
            for (int i = 0; i < 4; ++i) {
                const unsigned u0 = __float_as_uint(bf[2 * i]);
                const unsigned u1 = __float_as_uint(bf[2 * i + 1]);
                BH.u[i] = __builtin_amdgcn_perm(u1, u0, 0x07060302u);
                const float l0 = bf[2 * i]     - __uint_as_float(u0 & 0xFFFF0000u);
                const float l1 = bf[2 * i + 1] - __uint_as_float(u1 & 0xFFFF0000u);
                BL.u[i] = __builtin_amdgcn_perm(__float_as_uint(l1), __float_as_uint(l0),
                                                0x07060302u);
            }
            f32x4 a = (df == 0) ? acc0 : acc1;
            a = __builtin_amdgcn_mfma_f32_16x16x32_bf16(AH.v, BH.v, a, 0, 0, 0);
            a = __builtin_amdgcn_mfma_f32_16x16x32_bf16(AH.v, BL.v, a, 0, 0, 0);
            a = __builtin_amdgcn_mfma_f32_16x16x32_bf16(AL.v, BH.v, a, 0, 0, 0);
            if (df == 0) acc0 = a; else acc1 = a;
        }
    }

    // C/D layout: col = lane&15, row = (lane>>4)*4 + reg  [m89-verified]
    #pragma unroll
    for (int r = 0; r < 4; ++r) {
        Pr[g * 4 + r][dq +  0 + l15] = acc0[r];
        Pr[g * 4 + r][dq + 16 + l15] = acc1[r];
    }
    __syncthreads();

    // Snapshot both pr rows, then Pr's LDS is recycled as staging space.
    const float4 prA = *reinterpret_cast<const float4*>(&Pr[w * 2 + 0][lane * 4]);
    const float4 prB = *reinterpret_cast<const float4*>(&Pr[w * 2 + 1][lane * 4]);
    __syncthreads();

    // ---------------- Phase B: pipelined, 2 pids per wave ------------------
    const int pidA = pid0 + w * 2 + 0;
    const int pidB = pid0 + w * 2 + 1;
    const int bb   = pidA >> 10;           // same batch for both (pids within 16-blk)

    const float2 posA = *reinterpret_cast<const float2*>(&p_t[pidA * 2]);
    const float2 posB = *reinterpret_cast<const float2*>(&p_t[pidB * 2]);

    // ---- Geometry pid A (full) ----
    float reA[3], ceA[5];
    int rowA[3], colA[5];
    {
        const int p0 = (int)posA.x, p1 = (int)posA.y;
        #pragma unroll
        for (int i = 0; i < 3; ++i) {
            int rr = p0 + i;
            rr = rr > ROWS ? ROWS : rr;
            rr = (rr == ROWS) ? 0 : rr;
            rowA[i] = rr;
            const float rf = (float)(rr - 1 > 0 ? rr - 1 : 0);
            const float dr = rf - posA.x;
            reA[i] = __expf(-2.0f * dr * dr);
        }
        #pragma unroll
        for (int j = 0; j < 5; ++j) {
            int cc = p1 + j - 1;
            cc = cc < 0 ? 0 : (cc > COLS ? COLS : cc);
            cc = (cc == COLS) ? 0 : cc;
            colA[j] = cc;
            const float cf = (float)(cc - 1 > 0 ? cc - 1 : 0);
            const float dc = (cf - posA.y) * 0.5f;
            ceA[j] = __expf(-2.0f * dc * dc);
        }
    }
    // ---- Geometry pid B (indices only; re/ce later, overlapped) ----
    int rowB[3], colB[5];
    {
        const int p0 = (int)posB.x, p1 = (int)posB.y;
        #pragma unroll
        for (int i = 0; i < 3; ++i) {
            int rr = p0 + i;
            rr = rr > ROWS ? ROWS : rr;
            rr = (rr == ROWS) ? 0 : rr;
            rowB[i] = rr;
        }
        #pragma unroll
        for (int j = 0; j < 5; ++j) {
            int cc = p1 + j - 1;
            cc = cc < 0 ? 0 : (cc > COLS ? COLS : cc);
            cc = (cc == COLS) ? 0 : cc;
            colB[j] = cc;
        }
    }

    // ---- Issue pid A: rows 0..8 -> regs, 9..14 -> LDS slab ----
    float4 qgA[NREG];
    unsigned vmA = 0;
    #pragma unroll
    for (int k = 0; k < KWIN; ++k) {
        const int i = k / 5, j = k % 5;
        const int rr = rowA[i], cc = colA[j];
        const bool valid = (rr != 0) && (cc != 0);
        const float* src =
            &q[((size_t)((bb * HGRID + rr - 1) * WGRID + cc - 1)) * DDIM + lane * 4];
        if (k < NREG) {
            float4 v = make_float4(0.f, 0.f, 0.f, 0.f);
            if (valid) v = *reinterpret_cast<const float4*>(src);
            qgA[k] = v;
        } else {
            if (valid) gload_lds16(src, &qsw[(k - NREG) * DDIM]);
        }
        if (valid) vmA |= (1u << k);
    }

    __builtin_amdgcn_sched_barrier(0);   // pin issue order: A-loads before B-loads

    // ---- Issue pid B: rows 0..8 -> regs (fly under A's compute) ----
    float4 qgB[NREG];
    unsigned vmB = 0;
    #pragma unroll
    for (int k = 0; k < NREG; ++k) {
        const int i = k / 5, j = k % 5;
        const int rr = rowB[i], cc = colB[j];
        const bool valid = (rr != 0) && (cc != 0);
        float4 v = make_float4(0.f, 0.f, 0.f, 0.f);
        if (valid) {
            v = *reinterpret_cast<const float4*>(
                &q[((size_t)((bb * HGRID + rr - 1) * WGRID + cc - 1)) * DDIM + lane * 4]);
            vmB |= (1u << k);
        }
        qgB[k] = v;
    }
    #pragma unroll
    for (int k = NREG; k < KWIN; ++k) {
        const int i = k / 5, j = k % 5;
        if ((rowB[i] != 0) && (colB[j] != 0)) vmB |= (1u << k);
    }

    // ---- Wait: pid A's 15 loads done (9 newer B-loads may remain) ----
    asm volatile("s_waitcnt vmcnt(9)" ::: "memory");
    #pragma unroll
    for (int k = 0; k < NREG; ++k)
        asm volatile("" : "+v"(qgA[k].x), "+v"(qgA[k].y), "+v"(qgA[k].z), "+v"(qgA[k].w));

    // ================= Compute pid A =================
    {
        float score[KWIN];
        #pragma unroll
        for (int k = 0; k < NREG; ++k) {
            const float4 v = qgA[k];
            score[k] = fmaf(v.x, prA.x, fmaf(v.y, prA.y, fmaf(v.z, prA.z, v.w * prA.w)));
        }
        #pragma unroll
        for (int k = NREG; k < KWIN; ++k) {
            const float4 v =
                *reinterpret_cast<const float4*>(&qsw[(k - NREG) * DDIM + lane * 4]);
            score[k] = fmaf(v.x, prA.x, fmaf(v.y, prA.y, fmaf(v.z, prA.z, v.w * prA.w)));
        }
        #pragma unroll
        for (int k = 0; k < KWIN; ++k) {
            float s = score[k];
            #pragma unroll
            for (int off = 32; off; off >>= 1) s += __shfl_xor(s, off, 64);
            score[k] = ((vmA >> k) & 1u) ? s : -INFINITY;
        }
        float mx = score[0];
        #pragma unroll
        for (int k = 1; k < KWIN; ++k) mx = fmaxf(mx, score[k]);
        float sum = 0.f;
        #pragma unroll
        for (int k = 0; k < KWIN; ++k) {
            const float e = __expf(score[k] - mx);
            score[k] = e;
            sum += e;
        }
        const float inv = 1.0f / sum;

        float ox = 0.f, oy = 0.f, oz = 0.f, ow = 0.f;
        #pragma unroll
        for (int k = 0; k < KWIN; ++k) {
            const int i = k / 5, j = k % 5;
            const float wk2 = score[k] * inv * reA[i] * ceA[j];
            if (k < NREG) {
                ox = fmaf(wk2, qgA[k].x, ox);
                oy = fmaf(wk2, qgA[k].y, oy);
                oz = fmaf(wk2, qgA[k].z, oz);
                ow = fmaf(wk2, qgA[k].w, ow);
            } else if ((vmA >> k) & 1u) {
                const float4 v =
                    *reinterpret_cast<const float4*>(&qsw[(k - NREG) * DDIM + lane * 4]);
                ox = fmaf(wk2, v.x, ox);
                oy = fmaf(wk2, v.y, oy);
                oz = fmaf(wk2, v.z, oz);
                ow = fmaf(wk2, v.w, ow);
            }
        }
        *reinterpret_cast<float4*>(&out[(size_t)pidA * DDIM + lane * 4]) =
            make_float4(ox, oy, oz, ow);
    }

    // ---- Slab free: fence my LDS reads, then issue pid B's 6 LDS rows ----
    asm volatile("s_waitcnt lgkmcnt(0)" ::: "memory");
    __builtin_amdgcn_sched_barrier(0);
    #pragma unroll
    for (int k = NREG; k < KWIN; ++k) {
        const int i = k / 5, j = k % 5;
        const int rr = rowB[i], cc = colB[j];
        if ((rr != 0) && (cc != 0)) {
            gload_lds16(&q[((size_t)((bb * HGRID + rr - 1) * WGRID + cc - 1)) * DDIM
                           + lane * 4],
                        &qsw[(k - NREG) * DDIM]);
        }
    }

    // ---- Overlap: compute pid B's re/ce while LDS loads fly ----
    float reB[3], ceB[5];
    {
        #pragma unroll
        for (int i = 0; i < 3; ++i) {
            const int rr = rowB[i];
            const float rf = (float)(rr - 1 > 0 ? rr - 1 : 0);
            const float dr = rf - posB.x;
            reB[i] = __expf(-2.0f * dr * dr);
        }
        #pragma unroll
        for (int j = 0; j < 5; ++j) {
            const int cc = colB[j];
            const float cf = (float)(cc - 1 > 0 ? cc - 1 : 0);
            const float dc = (cf - posB.y) * 0.5f;
            ceB[j] = __expf(-2.0f * dc * dc);
        }
    }

    asm volatile("s_waitcnt vmcnt(0)" ::: "memory");
    #pragma unroll
    for (int k = 0; k < NREG; ++k)
        asm volatile("" : "+v"(qgB[k].x), "+v"(qgB[k].y), "+v"(qgB[k].z), "+v"(qgB[k].w));

    // ================= Compute pid B =================
    {
        float score[KWIN];
        #pragma unroll
        for (int k = 0; k < NREG; ++k) {
            const float4 v = qgB[k];
            score[k] = fmaf(v.x, prB.x, fmaf(v.y, prB.y, fmaf(v.z, prB.z, v.w * prB.w)));
        }
        #pragma unroll
        for (int k = NREG; k < KWIN; ++k) {
            const float4 v =
                *reinterpret_cast<const float4*>(&qsw[(k - NREG) * DDIM + lane * 4]);
            score[k] = fmaf(v.x, prB.x, fmaf(v.y, prB.y, fmaf(v.z, prB.z, v.w * prB.w)));
        }
        #pragma unroll
        for (int k = 0; k < KWIN; ++k) {
            float s = score[k];
            #pragma unroll
            for (int off = 32; off; off >>= 1) s += __shfl_xor(s, off, 64);
            score[k] = ((vmB >> k) & 1u) ? s : -INFINITY;
        }
        float mx = score[0];
        #pragma unroll
        for (int k = 1; k < KWIN; ++k) mx = fmaxf(mx, score[k]);
        float sum = 0.f;
        #pragma unroll
        for (int k = 0; k < KWIN; ++k) {
            const float e = __expf(score[k] - mx);
            score[k] = e;
            sum += e;
        }
        const float inv = 1.0f / sum;

        float ox = 0.f, oy = 0.f, oz = 0.f, ow = 0.f;
        #pragma unroll
        for (int k = 0; k < KWIN; ++k) {
            const int i = k / 5, j = k % 5;
            const float wk2 = score[k] * inv * reB[i] * ceB[j];
            if (k < NREG) {
                ox = fmaf(wk2, qgB[k].x, ox);
                oy = fmaf(wk2, qgB[k].y, oy);
                oz = fmaf(wk2, qgB[k].z, oz);
                ow = fmaf(wk2, qgB[k].w, ow);
            } else if ((vmB >> k) & 1u) {
                const float4 v =
                    *reinterpret_cast<const float4*>(&qsw[(k - NREG) * DDIM + lane * 4]);
                ox = fmaf(wk2, v.x, ox);
                oy = fmaf(wk2, v.y, oy);
                oz = fmaf(wk2, v.z, oz);
                ow = fmaf(wk2, v.w, ow);
            }
        }
        *reinterpret_cast<float4*>(&out[(size_t)pidB * DDIM + lane * 4]) =
            make_float4(ox, oy, oz, ow);
    }
}

// ---------------------------------------------------------------------------
extern "C" void kernel_launch(void* const* d_in, const int* in_sizes, int n_in,
                              void* d_out, int out_size, void* d_ws, size_t ws_size,
                              hipStream_t stream) {
    const float* q   = (const float*)d_in[0];
    const float* c_t = (const float*)d_in[1];
    const float* p_t = (const float*)d_in[2];
    const float* W_a = (const float*)d_in[3];
    float* out = (float*)d_out;

    fused_local_attn<<<BN / PIDS_PER_BLK, THREADS, 0, stream>>>(q, c_t, p_t, W_a, out);
}